// Round 1
// baseline (103.193 us; speedup 1.0000x reference)
//
#include <hip/hip_runtime.h>
#include <hip/hip_bf16.h>

#define KN 4096
#define CN 10
#define DN 128
#define BN 1000
#define LN 512

typedef float f32x4 __attribute__((ext_vector_type(4)));
typedef short bf16x8 __attribute__((ext_vector_type(8)));

// ---------------- prep: embs fp32 -> bf16, sqn[k] = ||e_k||^2 (fp32 exact) ----
__global__ __launch_bounds__(64) void w2v_prep(const float* __restrict__ embs,
                                               float* __restrict__ sqn,
                                               short* __restrict__ ebf) {
    int r = blockIdx.x;          // 4096 blocks, one row each
    int lane = threadIdx.x;      // 64 lanes
    const float* row = embs + r * DN;
    float a0 = row[lane];
    float a1 = row[lane + 64];
    __hip_bfloat16 h0 = __float2bfloat16(a0);
    __hip_bfloat16 h1 = __float2bfloat16(a1);
    short* orow = ebf + r * DN;
    orow[lane]      = *reinterpret_cast<short*>(&h0);
    orow[lane + 64] = *reinterpret_cast<short*>(&h1);
    float s = a0 * a0 + a1 * a1;
    #pragma unroll
    for (int off = 32; off > 0; off >>= 1) s += __shfl_down(s, off, 64);
    if (lane == 0) sqn[r] = s;
}

// ---------------- supervised: gather-sum -> logits -> log_softmax ------------
__global__ __launch_bounds__(128) void w2v_sup(const float* __restrict__ embs,
                                               const int* __restrict__ reads,
                                               const int* __restrict__ labels,
                                               const float* __restrict__ W,
                                               float* __restrict__ acc) {
    __shared__ int   sidx[LN];
    __shared__ float remb[DN];
    __shared__ float slog[CN];
    int b = blockIdx.x, t = threadIdx.x;
    for (int i = t; i < LN; i += 128) sidx[i] = reads[b * LN + i];
    __syncthreads();
    float a0 = 0.f, a1 = 0.f, a2 = 0.f, a3 = 0.f;
    #pragma unroll 4
    for (int l = 0; l < LN; l += 4) {
        a0 += embs[sidx[l + 0] * DN + t];
        a1 += embs[sidx[l + 1] * DN + t];
        a2 += embs[sidx[l + 2] * DN + t];
        a3 += embs[sidx[l + 3] * DN + t];
    }
    remb[t] = (a0 + a1) + (a2 + a3);
    __syncthreads();
    if (t < CN) {
        float s = 0.f;
        #pragma unroll 8
        for (int d = 0; d < DN; ++d) s += remb[d] * W[t * DN + d];
        slog[t] = s;
    }
    __syncthreads();
    if (t == 0) {
        float m = slog[0];
        #pragma unroll
        for (int c = 1; c < CN; ++c) m = fmaxf(m, slog[c]);
        float se = 0.f;
        #pragma unroll
        for (int c = 0; c < CN; ++c) se += __expf(slog[c] - m);
        float lse = m + __logf(se);
        float lp = slog[labels[b]] - lse;
        atomicAdd(acc, -lp);   // supervised partial
    }
}

// ---------------- unsupervised: bf16 MFMA Gram tile + pc-stream epilogue -----
// 128x128 C-tile per block, 4 waves in 2x2, each wave 64x64 (4x4 MFMA tiles).
__global__ __launch_bounds__(256) void w2v_unsup(const short* __restrict__ ebf,
                                                 const float* __restrict__ sqn,
                                                 const float* __restrict__ pc,
                                                 float* __restrict__ acc) {
    __shared__ char  ldsA[32768];   // Ei tile: 128 rows x 128 bf16, XOR-swizzled
    __shared__ char  ldsB[32768];   // Ej tile
    __shared__ float sqi[128];
    __shared__ float sqj[128];
    __shared__ float red[256];

    int t  = threadIdx.x;
    int i0 = blockIdx.y * 128;
    int j0 = blockIdx.x * 128;

    // stage tiles (flat 32KB copies), swizzle: byte ^= (row&7)<<4
    const uint4* gA = (const uint4*)(ebf + i0 * DN);
    const uint4* gB = (const uint4*)(ebf + j0 * DN);
    for (int c = t; c < 2048; c += 256) {
        int o   = c << 4;            // byte offset, 16B chunks
        int row = o >> 8;            // 256B per row
        int dst = o ^ ((row & 7) << 4);
        *(uint4*)(ldsA + dst) = gA[c];
        *(uint4*)(ldsB + dst) = gB[c];
    }
    if (t < 128) { sqi[t] = sqn[i0 + t]; sqj[t] = sqn[j0 + t]; }
    __syncthreads();

    int wave = t >> 6, lane = t & 63;
    int wr = (wave >> 1) * 64;       // wave row offset in C-tile
    int wc = (wave & 1) * 64;        // wave col offset
    int lr = lane & 15;              // fragment row/col index
    int lg = lane >> 4;              // k-group

    f32x4 acc4[4][4];
    #pragma unroll
    for (int mi = 0; mi < 4; ++mi)
        #pragma unroll
        for (int nj = 0; nj < 4; ++nj)
            acc4[mi][nj] = (f32x4){0.f, 0.f, 0.f, 0.f};

    #pragma unroll
    for (int kk = 0; kk < 4; ++kk) {          // K = 128 = 4 x 32
        bf16x8 afr[4], bfr[4];
        #pragma unroll
        for (int mi = 0; mi < 4; ++mi) {
            int rowa = wr + 16 * mi + lr;
            int offa = rowa * 256 + kk * 64 + lg * 16;
            afr[mi] = *(bf16x8*)(ldsA + (offa ^ ((rowa & 7) << 4)));
            int rowb = wc + 16 * mi + lr;
            int offb = rowb * 256 + kk * 64 + lg * 16;
            bfr[mi] = *(bf16x8*)(ldsB + (offb ^ ((rowb & 7) << 4)));
        }
        #pragma unroll
        for (int mi = 0; mi < 4; ++mi)
            #pragma unroll
            for (int nj = 0; nj < 4; ++nj)
                acc4[mi][nj] = __builtin_amdgcn_mfma_f32_16x16x32_bf16(
                    afr[mi], bfr[nj], acc4[mi][nj], 0, 0, 0);
    }

    // epilogue: stream pair_counts, accumulate pc*dist + exp(-dist) on nonzeros
    float part = 0.f;
    #pragma unroll
    for (int mi = 0; mi < 4; ++mi) {
        #pragma unroll
        for (int nj = 0; nj < 4; ++nj) {
            int col_l = wc + 16 * nj + lr;          // C/D: col = lane&15
            int gj = j0 + col_l;
            float sj = sqj[col_l];
            #pragma unroll
            for (int v = 0; v < 4; ++v) {           // row = (lane>>4)*4 + v
                int row_l = wr + 16 * mi + lg * 4 + v;
                int gi = i0 + row_l;
                float p = pc[gi * KN + gj];
                if (p != 0.f) {
                    float sq = sqi[row_l] + sj - 2.f * acc4[mi][nj][v];
                    sq = fmaxf(sq, 0.f);
                    float dd = sqrtf(sq);
                    part += p * dd + __expf(-dd);
                }
            }
        }
    }
    red[t] = part;
    __syncthreads();
    for (int s = 128; s >= 1; s >>= 1) {
        if (t < s) red[t] += red[t + s];
        __syncthreads();
    }
    if (t == 0) atomicAdd(acc + 1, red[0]);  // unsupervised positive-sum
}

// ---------------- combine -----------------------------------------------------
__global__ void w2v_final(const float* __restrict__ acc,
                          const float* __restrict__ delta,
                          float* __restrict__ out) {
    float sup = acc[0];
    float uns = acc[1] * (1.f / 16777216.f);   // 1/(4096^2)
    float d = delta[0];
    out[0] = d * sup + (1.f - d) * uns;
}

extern "C" void kernel_launch(void* const* d_in, const int* in_sizes, int n_in,
                              void* d_out, int out_size, void* d_ws, size_t ws_size,
                              hipStream_t stream) {
    const float* pc     = (const float*)d_in[0];
    const int*   reads  = (const int*)  d_in[1];
    const int*   labels = (const int*)  d_in[2];
    const float* delta  = (const float*)d_in[3];
    const float* embs   = (const float*)d_in[4];
    const float* W      = (const float*)d_in[5];
    float* out = (float*)d_out;

    char*  ws  = (char*)d_ws;
    float* acc = (float*)ws;                          // 2 floats
    float* sqn = (float*)(ws + 4096);                 // 4096 f32
    short* ebf = (short*)(ws + 4096 + KN * 4);        // 4096x128 bf16 (1 MB)

    hipMemsetAsync(acc, 0, 2 * sizeof(float), stream);
    w2v_prep<<<KN, 64, 0, stream>>>(embs, sqn, ebf);
    w2v_sup<<<BN, 128, 0, stream>>>(embs, reads, labels, W, acc);
    w2v_unsup<<<dim3(32, 32), 256, 0, stream>>>(ebf, sqn, pc, acc);
    w2v_final<<<1, 1, 0, stream>>>(acc, delta, out);
}

// Round 2
// 80.705 us; speedup vs baseline: 1.2786x; 1.2786x over previous
//
#include <hip/hip_runtime.h>
#include <hip/hip_bf16.h>

#define KN 4096
#define CN 10
#define DN 128
#define BN 1000
#define LN 512

typedef float f32x4 __attribute__((ext_vector_type(4)));
typedef short bf16x8 __attribute__((ext_vector_type(8)));

// ---------------- prep: embs fp32 -> bf16, sqn[k] = ||e_k||^2 (fp32 exact) ----
__global__ __launch_bounds__(64) void w2v_prep(const float* __restrict__ embs,
                                               float* __restrict__ sqn,
                                               short* __restrict__ ebf) {
    int r = blockIdx.x;          // 4096 blocks, one row each
    int lane = threadIdx.x;      // 64 lanes
    const float* row = embs + r * DN;
    float a0 = row[lane];
    float a1 = row[lane + 64];
    __hip_bfloat16 h0 = __float2bfloat16(a0);
    __hip_bfloat16 h1 = __float2bfloat16(a1);
    short* orow = ebf + r * DN;
    orow[lane]      = *reinterpret_cast<short*>(&h0);
    orow[lane + 64] = *reinterpret_cast<short*>(&h1);
    float s = a0 * a0 + a1 * a1;
    #pragma unroll
    for (int off = 32; off > 0; off >>= 1) s += __shfl_down(s, off, 64);
    if (lane == 0) sqn[r] = s;
}

// ---------------- supervised: gather-sum -> logits -> log_softmax ------------
__global__ __launch_bounds__(128) void w2v_sup(const float* __restrict__ embs,
                                               const int* __restrict__ reads,
                                               const int* __restrict__ labels,
                                               const float* __restrict__ W,
                                               float* __restrict__ acc) {
    __shared__ int   sidx[LN];
    __shared__ float remb[DN];
    __shared__ float slog[CN];
    int b = blockIdx.x, t = threadIdx.x;
    for (int i = t; i < LN; i += 128) sidx[i] = reads[b * LN + i];
    __syncthreads();
    float a0 = 0.f, a1 = 0.f, a2 = 0.f, a3 = 0.f;
    #pragma unroll 4
    for (int l = 0; l < LN; l += 4) {
        a0 += embs[sidx[l + 0] * DN + t];
        a1 += embs[sidx[l + 1] * DN + t];
        a2 += embs[sidx[l + 2] * DN + t];
        a3 += embs[sidx[l + 3] * DN + t];
    }
    remb[t] = (a0 + a1) + (a2 + a3);
    __syncthreads();
    if (t < CN) {
        float s = 0.f;
        #pragma unroll 8
        for (int d = 0; d < DN; ++d) s += remb[d] * W[t * DN + d];
        slog[t] = s;
    }
    __syncthreads();
    if (t == 0) {
        float m = slog[0];
        #pragma unroll
        for (int c = 1; c < CN; ++c) m = fmaxf(m, slog[c]);
        float se = 0.f;
        #pragma unroll
        for (int c = 0; c < CN; ++c) se += __expf(slog[c] - m);
        float lse = m + __logf(se);
        float lp = slog[labels[b]] - lse;
        atomicAdd(acc, -lp);   // supervised partial
    }
}

// ---------------- unsupervised: LDS-free bf16 MFMA Gram + pc-stream epilogue --
// 128x128 C-tile per block, 4 waves in 2x2, each wave 64x64 (4x4 MFMA tiles).
// A/B fragments load straight from global (ebf is 1MB, L2-resident); only
// 1KB LDS (sqi/sqj + wave partials) -> occupancy capped by VGPR/threads only.
__global__ __launch_bounds__(256, 4) void w2v_unsup(const short* __restrict__ ebf,
                                                    const float* __restrict__ sqn,
                                                    const float* __restrict__ pc,
                                                    float* __restrict__ acc) {
    __shared__ float sqi[128];
    __shared__ float sqj[128];
    __shared__ float wred[4];

    int t  = threadIdx.x;
    int i0 = blockIdx.y * 128;
    int j0 = blockIdx.x * 128;

    if (t < 128) sqi[t] = sqn[i0 + t];
    else         sqj[t - 128] = sqn[j0 + t - 128];

    int wave = t >> 6, lane = t & 63;
    int wr = (wave >> 1) * 64;       // wave row offset in C-tile
    int wc = (wave & 1) * 64;        // wave col offset
    int lr = lane & 15;              // fragment row/col index
    int lg = lane >> 4;              // k-group

    const short* Ai = ebf + (size_t)(i0 + wr + lr) * DN;   // + mi*16*DN per mi
    const short* Bj = ebf + (size_t)(j0 + wc + lr) * DN;   // + nj*16*DN per nj

    f32x4 acc4[4][4];
    #pragma unroll
    for (int mi = 0; mi < 4; ++mi)
        #pragma unroll
        for (int nj = 0; nj < 4; ++nj)
            acc4[mi][nj] = (f32x4){0.f, 0.f, 0.f, 0.f};

    #pragma unroll
    for (int kk = 0; kk < 4; ++kk) {          // K = 128 = 4 x 32
        int ko = kk * 32 + lg * 8;            // element offset within row
        bf16x8 afr[4], bfr[4];
        #pragma unroll
        for (int mi = 0; mi < 4; ++mi) {
            afr[mi] = *(const bf16x8*)(Ai + (size_t)mi * 16 * DN + ko);
            bfr[mi] = *(const bf16x8*)(Bj + (size_t)mi * 16 * DN + ko);
        }
        #pragma unroll
        for (int mi = 0; mi < 4; ++mi)
            #pragma unroll
            for (int nj = 0; nj < 4; ++nj)
                acc4[mi][nj] = __builtin_amdgcn_mfma_f32_16x16x32_bf16(
                    afr[mi], bfr[nj], acc4[mi][nj], 0, 0, 0);
    }

    __syncthreads();   // sqi/sqj visible (overlaps with MFMA latency)

    // epilogue: stream pair_counts, branchless accumulate over nonzeros
    float sj0 = sqj[wc + lr], sj1 = sqj[wc + 16 + lr];
    float sj2 = sqj[wc + 32 + lr], sj3 = sqj[wc + 48 + lr];
    float part = 0.f;
    #pragma unroll
    for (int mi = 0; mi < 4; ++mi) {
        #pragma unroll
        for (int v = 0; v < 4; ++v) {         // C/D row = (lane>>4)*4 + v
            int row_l = wr + 16 * mi + lg * 4 + v;
            float si = sqi[row_l];
            const float* prow = pc + (size_t)(i0 + row_l) * KN + (j0 + wc + lr);
            float p0 = prow[0];
            float p1 = prow[16];
            float p2 = prow[32];
            float p3 = prow[48];
            float sq0 = fmaxf(si + sj0 - 2.f * acc4[mi][0][v], 0.f);
            float sq1 = fmaxf(si + sj1 - 2.f * acc4[mi][1][v], 0.f);
            float sq2 = fmaxf(si + sj2 - 2.f * acc4[mi][2][v], 0.f);
            float sq3 = fmaxf(si + sj3 - 2.f * acc4[mi][3][v], 0.f);
            float d0 = sqrtf(sq0), d1 = sqrtf(sq1), d2 = sqrtf(sq2), d3 = sqrtf(sq3);
            float t0 = fmaf(p0, d0, __expf(-d0));
            float t1 = fmaf(p1, d1, __expf(-d1));
            float t2 = fmaf(p2, d2, __expf(-d2));
            float t3 = fmaf(p3, d3, __expf(-d3));
            part += (p0 != 0.f) ? t0 : 0.f;
            part += (p1 != 0.f) ? t1 : 0.f;
            part += (p2 != 0.f) ? t2 : 0.f;
            part += (p3 != 0.f) ? t3 : 0.f;
        }
    }
    #pragma unroll
    for (int off = 32; off > 0; off >>= 1) part += __shfl_down(part, off, 64);
    if (lane == 0) wred[wave] = part;
    __syncthreads();
    if (t == 0) {
        float s = (wred[0] + wred[1]) + (wred[2] + wred[3]);
        atomicAdd(acc + 1, s);  // unsupervised positive-sum
    }
}

// ---------------- combine -----------------------------------------------------
__global__ void w2v_final(const float* __restrict__ acc,
                          const float* __restrict__ delta,
                          float* __restrict__ out) {
    float sup = acc[0];
    float uns = acc[1] * (1.f / 16777216.f);   // 1/(4096^2)
    float d = delta[0];
    out[0] = d * sup + (1.f - d) * uns;
}

extern "C" void kernel_launch(void* const* d_in, const int* in_sizes, int n_in,
                              void* d_out, int out_size, void* d_ws, size_t ws_size,
                              hipStream_t stream) {
    const float* pc     = (const float*)d_in[0];
    const int*   reads  = (const int*)  d_in[1];
    const int*   labels = (const int*)  d_in[2];
    const float* delta  = (const float*)d_in[3];
    const float* embs   = (const float*)d_in[4];
    const float* W      = (const float*)d_in[5];
    float* out = (float*)d_out;

    char*  ws  = (char*)d_ws;
    float* acc = (float*)ws;                          // 2 floats
    float* sqn = (float*)(ws + 4096);                 // 4096 f32
    short* ebf = (short*)(ws + 4096 + KN * 4);        // 4096x128 bf16 (1 MB)

    hipMemsetAsync(acc, 0, 2 * sizeof(float), stream);
    w2v_prep<<<KN, 64, 0, stream>>>(embs, sqn, ebf);
    w2v_sup<<<BN, 128, 0, stream>>>(embs, reads, labels, W, acc);
    w2v_unsup<<<dim3(32, 32), 256, 0, stream>>>(ebf, sqn, pc, acc);
    w2v_final<<<1, 1, 0, stream>>>(acc, delta, out);
}

// Round 3
// 69.579 us; speedup vs baseline: 1.4831x; 1.1599x over previous
//
#include <hip/hip_runtime.h>
#include <hip/hip_bf16.h>

#define KN 4096
#define CN 10
#define DN 128
#define BN 1000
#define LN 512
#define PREP_BLOCKS 512   // 8 emb rows each

typedef float f32x4 __attribute__((ext_vector_type(4)));
typedef short bf16x8 __attribute__((ext_vector_type(8)));

__device__ __forceinline__ short bf16bits(float x) {
    __hip_bfloat16 h = __float2bfloat16(x);
    return *reinterpret_cast<short*>(&h);
}
__device__ __forceinline__ float bflo(unsigned u) {  // low bf16 of packed u32
    unsigned v = u << 16;
    return *reinterpret_cast<float*>(&v);
}
__device__ __forceinline__ float bfhi(unsigned u) {  // high bf16
    unsigned v = u & 0xFFFF0000u;
    return *reinterpret_cast<float*>(&v);
}

// ---------------- fused: prep (blocks 0..511) + supervised (blocks 512..1511) --
__global__ __launch_bounds__(256) void w2v_fused(const float* __restrict__ embs,
                                                 const int* __restrict__ reads,
                                                 const int* __restrict__ labels,
                                                 const float* __restrict__ W,
                                                 float* __restrict__ acc,
                                                 float* __restrict__ sqn,
                                                 short* __restrict__ ebf) {
    int blk = blockIdx.x;
    int t = threadIdx.x;
    if (blk < PREP_BLOCKS) {
        // ---- prep: fp32 -> bf16 + row sqnorm, 8 rows per block ----
        int row = t >> 5, lane = t & 31;
        int r = blk * 8 + row;
        float4 v = ((const float4*)embs)[r * 32 + lane];
        short4 s4;
        s4.x = bf16bits(v.x); s4.y = bf16bits(v.y);
        s4.z = bf16bits(v.z); s4.w = bf16bits(v.w);
        ((short4*)ebf)[r * 32 + lane] = s4;
        float ss = v.x * v.x + v.y * v.y + v.z * v.z + v.w * v.w;
        #pragma unroll
        for (int m = 16; m >= 1; m >>= 1) ss += __shfl_xor(ss, m, 64);
        if (lane == 0) sqn[r] = ss;
        return;
    }
    // ---- supervised ----
    int b = blk - PREP_BLOCKS;
    __shared__ int    sidx[LN];
    __shared__ float4 red4[8][32];
    __shared__ float  remb[DN];
    __shared__ float  slog[CN];
    for (int i = t; i < LN; i += 256) sidx[i] = reads[b * LN + i];
    __syncthreads();
    int g = t >> 5, lane = t & 31;
    const float4* e4 = (const float4*)embs;
    float4 s = {0.f, 0.f, 0.f, 0.f};
    #pragma unroll 8
    for (int l = 0; l < 64; ++l) {
        int idx = sidx[g * 64 + l];
        float4 v = e4[(size_t)idx * 32 + lane];
        s.x += v.x; s.y += v.y; s.z += v.z; s.w += v.w;
    }
    red4[g][lane] = s;
    __syncthreads();
    if (t < 32) {
        float4 r = red4[0][t];
        #pragma unroll
        for (int g2 = 1; g2 < 8; ++g2) {
            float4 v = red4[g2][t];
            r.x += v.x; r.y += v.y; r.z += v.z; r.w += v.w;
        }
        ((float4*)remb)[t] = r;
    }
    __syncthreads();
    if (t < CN) {
        const float4* w4 = (const float4*)(W + t * DN);
        const float4* r4 = (const float4*)remb;
        float sum = 0.f;
        #pragma unroll 8
        for (int d = 0; d < 32; ++d) {
            float4 wv = w4[d]; float4 rv = r4[d];
            sum += wv.x * rv.x + wv.y * rv.y + wv.z * rv.z + wv.w * rv.w;
        }
        slog[t] = sum;
    }
    __syncthreads();
    if (t == 0) {
        float m = slog[0];
        #pragma unroll
        for (int c = 1; c < CN; ++c) m = fmaxf(m, slog[c]);
        float se = 0.f;
        #pragma unroll
        for (int c = 0; c < CN; ++c) se += __expf(slog[c] - m);
        float lse = m + __logf(se);
        float lp = slog[labels[b]] - lse;
        atomicAdd(acc, -lp);
    }
}

// ---------------- unsupervised --------------------------------------------------
// Phase 1: bf16 MFMA Gram 128x128 per block (fragments straight from L2-resident ebf)
// Phase 2: dist -> bf16 LDS tile (XOR-swizzled rows)
// Phase 3: stream pc with coalesced float4 loads, 8 in flight, masked accumulate
__global__ __launch_bounds__(256, 4) void w2v_unsup(const short* __restrict__ ebf,
                                                    const float* __restrict__ sqn,
                                                    const float* __restrict__ pc,
                                                    float* __restrict__ acc) {
    __shared__ char  dlds[32768];   // 128 x 128 bf16 dist tile, swizzled
    __shared__ float sqi[128];
    __shared__ float sqj[128];
    __shared__ float wred[4];

    int t  = threadIdx.x;
    int i0 = blockIdx.y * 128;
    int j0 = blockIdx.x * 128;

    if (t < 128) sqi[t] = sqn[i0 + t];
    else         sqj[t - 128] = sqn[j0 + t - 128];

    int wave = t >> 6, lane = t & 63;
    int wr = (wave >> 1) * 64;
    int wc = (wave & 1) * 64;
    int lr = lane & 15;
    int lg = lane >> 4;

    const short* Ai = ebf + (size_t)(i0 + wr + lr) * DN;
    const short* Bj = ebf + (size_t)(j0 + wc + lr) * DN;

    f32x4 acc4[4][4];
    #pragma unroll
    for (int mi = 0; mi < 4; ++mi)
        #pragma unroll
        for (int nj = 0; nj < 4; ++nj)
            acc4[mi][nj] = (f32x4){0.f, 0.f, 0.f, 0.f};

    #pragma unroll
    for (int kk = 0; kk < 4; ++kk) {
        int ko = kk * 32 + lg * 8;
        bf16x8 afr[4], bfr[4];
        #pragma unroll
        for (int mi = 0; mi < 4; ++mi) {
            afr[mi] = *(const bf16x8*)(Ai + (size_t)mi * 16 * DN + ko);
            bfr[mi] = *(const bf16x8*)(Bj + (size_t)mi * 16 * DN + ko);
        }
        #pragma unroll
        for (int mi = 0; mi < 4; ++mi)
            #pragma unroll
            for (int nj = 0; nj < 4; ++nj)
                acc4[mi][nj] = __builtin_amdgcn_mfma_f32_16x16x32_bf16(
                    afr[mi], bfr[nj], acc4[mi][nj], 0, 0, 0);
    }

    __syncthreads();   // sqi/sqj ready

    // Phase 2: dist -> bf16 LDS (byte = (row*256 + col*2) ^ ((row&7)<<4))
    #pragma unroll
    for (int mi = 0; mi < 4; ++mi) {
        #pragma unroll
        for (int v = 0; v < 4; ++v) {
            int row = wr + 16 * mi + lg * 4 + v;
            float si = sqi[row];
            int rbase = row * 256;
            int swz = (row & 7) << 4;
            #pragma unroll
            for (int nj = 0; nj < 4; ++nj) {
                int col = wc + 16 * nj + lr;
                float sq = fmaxf(si + sqj[col] - 2.f * acc4[mi][nj][v], 0.f);
                float dd = sqrtf(sq);
                *(short*)(dlds + ((rbase + col * 2) ^ swz)) = bf16bits(dd);
            }
        }
    }
    __syncthreads();

    // Phase 3: coalesced pc streaming. 256 threads cover 8 rows x 128 cols per pass.
    int rb = t >> 5;            // 0..7
    int c4 = t & 31;            // float4 column index
    int c8 = c4 * 8;            // byte offset of 4 bf16 dists
    float part = 0.f;
    #pragma unroll
    for (int grp = 0; grp < 2; ++grp) {
        float4 pcb[8];
        uint2  db[8];
        #pragma unroll
        for (int p = 0; p < 8; ++p) {
            int row = (grp * 8 + p) * 8 + rb;
            pcb[p] = ((const float4*)(pc + (size_t)(i0 + row) * KN + j0))[c4];
            db[p]  = *(const uint2*)(dlds + ((row * 256 + c8) ^ ((row & 7) << 4)));
        }
        #pragma unroll
        for (int p = 0; p < 8; ++p) {
            float d0 = bflo(db[p].x), d1 = bfhi(db[p].x);
            float d2 = bflo(db[p].y), d3 = bfhi(db[p].y);
            float t0 = fmaf(pcb[p].x, d0, __expf(-d0));
            float t1 = fmaf(pcb[p].y, d1, __expf(-d1));
            float t2 = fmaf(pcb[p].z, d2, __expf(-d2));
            float t3 = fmaf(pcb[p].w, d3, __expf(-d3));
            part += (pcb[p].x != 0.f) ? t0 : 0.f;
            part += (pcb[p].y != 0.f) ? t1 : 0.f;
            part += (pcb[p].z != 0.f) ? t2 : 0.f;
            part += (pcb[p].w != 0.f) ? t3 : 0.f;
        }
    }
    #pragma unroll
    for (int off = 32; off > 0; off >>= 1) part += __shfl_down(part, off, 64);
    if (lane == 0) wred[wave] = part;
    __syncthreads();
    if (t == 0) {
        float s = (wred[0] + wred[1]) + (wred[2] + wred[3]);
        atomicAdd(acc + 1, s);
    }
}

// ---------------- combine -------------------------------------------------------
__global__ void w2v_final(const float* __restrict__ acc,
                          const float* __restrict__ delta,
                          float* __restrict__ out) {
    float sup = acc[0];
    float uns = acc[1] * (1.f / 16777216.f);   // 1/(4096^2)
    float d = delta[0];
    out[0] = d * sup + (1.f - d) * uns;
}

extern "C" void kernel_launch(void* const* d_in, const int* in_sizes, int n_in,
                              void* d_out, int out_size, void* d_ws, size_t ws_size,
                              hipStream_t stream) {
    const float* pc     = (const float*)d_in[0];
    const int*   reads  = (const int*)  d_in[1];
    const int*   labels = (const int*)  d_in[2];
    const float* delta  = (const float*)d_in[3];
    const float* embs   = (const float*)d_in[4];
    const float* W      = (const float*)d_in[5];
    float* out = (float*)d_out;

    char*  ws  = (char*)d_ws;
    float* acc = (float*)ws;                          // 2 floats
    float* sqn = (float*)(ws + 4096);                 // 4096 f32
    short* ebf = (short*)(ws + 4096 + KN * 4);        // 4096x128 bf16 (1 MB)

    hipMemsetAsync(acc, 0, 2 * sizeof(float), stream);
    w2v_fused<<<PREP_BLOCKS + BN, 256, 0, stream>>>(embs, reads, labels, W, acc, sqn, ebf);
    w2v_unsup<<<dim3(32, 32), 256, 0, stream>>>(ebf, sqn, pc, acc);
    w2v_final<<<1, 1, 0, stream>>>(acc, delta, out);
}

// Round 4
// 55.503 us; speedup vs baseline: 1.8592x; 1.2536x over previous
//
#include <hip/hip_runtime.h>
#include <hip/hip_bf16.h>

#define KN 4096
#define CN 10
#define DN 128
#define BN 1000
#define LN 512

typedef float f32x4 __attribute__((ext_vector_type(4)));
typedef short bf16x8 __attribute__((ext_vector_type(8)));

__device__ __forceinline__ short bf16bits(float x) {
    __hip_bfloat16 h = __float2bfloat16(x);
    return *reinterpret_cast<short*>(&h);
}

// async global->LDS, 16B per lane, dest = wave-uniform base + lane*16
__device__ __forceinline__ void gload_lds16(const float* g, float* l) {
    __builtin_amdgcn_global_load_lds(
        (const __attribute__((address_space(1))) void*)g,
        (__attribute__((address_space(3))) void*)l, 16, 0, 0);
}

// ---------------- K1: prep (blocks 0..511) + P = embs @ W^T (blocks 512..575) --
__global__ __launch_bounds__(256) void w2v_prep(const float* __restrict__ embs,
                                                const float* __restrict__ W,
                                                float* __restrict__ sqn,
                                                short* __restrict__ ebf,
                                                float* __restrict__ P) {
    int blk = blockIdx.x, t = threadIdx.x;
    if (blk < 512) {
        // fp32 -> bf16 + row sqnorm, 8 rows per block
        int row = t >> 5, lane = t & 31;
        int r = blk * 8 + row;
        float4 v = ((const float4*)embs)[r * 32 + lane];
        short4 s4;
        s4.x = bf16bits(v.x); s4.y = bf16bits(v.y);
        s4.z = bf16bits(v.z); s4.w = bf16bits(v.w);
        ((short4*)ebf)[r * 32 + lane] = s4;
        float ss = v.x * v.x + v.y * v.y + v.z * v.z + v.w * v.w;
        #pragma unroll
        for (int m = 16; m >= 1; m >>= 1) ss += __shfl_xor(ss, m, 64);
        if (lane == 0) sqn[r] = ss;
        return;
    }
    // P rows: 64 blocks x 64 rows; 4 threads per row, each a 32-d quarter
    int pb = blk - 512;
    int r = pb * 64 + (t >> 2);
    int q = t & 3;
    const float4* er = (const float4*)(embs + (size_t)r * DN) + q * 8;
    const float4* w4 = (const float4*)W;   // W is 10x128, L1-hot broadcast
    float s[CN];
    #pragma unroll
    for (int c = 0; c < CN; ++c) s[c] = 0.f;
    #pragma unroll
    for (int d4 = 0; d4 < 8; ++d4) {
        float4 e = er[d4];
        #pragma unroll
        for (int c = 0; c < CN; ++c) {
            float4 w = w4[c * 32 + q * 8 + d4];
            s[c] += e.x * w.x + e.y * w.y + e.z * w.z + e.w * w.w;
        }
    }
    #pragma unroll
    for (int c = 0; c < CN; ++c) {
        s[c] += __shfl_xor(s[c], 1, 64);
        s[c] += __shfl_xor(s[c], 2, 64);
    }
    if (q == 0) {
        float* pr = P + (size_t)r * 12;     // rows padded to 12 floats (3 float4)
        #pragma unroll
        for (int c = 0; c < CN; ++c) pr[c] = s[c];
        pr[10] = 0.f; pr[11] = 0.f;
    }
}

// ---------------- K2: unsup (blocks 0..1023) + sup (blocks 1024..2023) ---------
struct UnsupSm {
    float pcT[128 * 128];   // pc tile, linear [row][col], filled by global_load_lds
    float sqi[128];
    float sqj[128];
    float wred[4];
};
struct SupSm {
    int   sidx[LN];
    float wredS[4][12];
    float slog[CN];
};
union K2Sm { UnsupSm u; SupSm s; };

__global__ __launch_bounds__(256, 2) void w2v_main(const short* __restrict__ ebf,
                                                   const float* __restrict__ sqn,
                                                   const float* __restrict__ pc,
                                                   const float* __restrict__ P,
                                                   const int* __restrict__ reads,
                                                   const int* __restrict__ labels,
                                                   float* __restrict__ psup,
                                                   float* __restrict__ puns) {
    __shared__ K2Sm sm;
    int blk = blockIdx.x, t = threadIdx.x;

    if (blk < 1024) {
        // ================= unsupervised 128x128 tile =================
        int i0 = (blk >> 5) * 128, j0 = (blk & 31) * 128;
        int wave = t >> 6, lane = t & 63;
        int wr = (wave >> 1) * 64, wc = (wave & 1) * 64;
        int lr = lane & 15, lg = lane >> 4;

        if (t < 128) sm.u.sqi[t] = sqn[i0 + t];
        else         sm.u.sqj[t - 128] = sqn[j0 + t - 128];

        // ---- ALL fragment loads first (vmcnt is FIFO: pc must be younger) ----
        const short* Ai = ebf + (size_t)(i0 + wr + lr) * DN;
        const short* Bj = ebf + (size_t)(j0 + wc + lr) * DN;
        bf16x8 afr[4][4], bfr[4][4];
        #pragma unroll
        for (int kk = 0; kk < 4; ++kk) {
            int ko = kk * 32 + lg * 8;
            #pragma unroll
            for (int mi = 0; mi < 4; ++mi) {
                afr[kk][mi] = *(const bf16x8*)(Ai + (size_t)mi * 16 * DN + ko);
                bfr[kk][mi] = *(const bf16x8*)(Bj + (size_t)mi * 16 * DN + ko);
            }
        }
        __builtin_amdgcn_sched_barrier(0);   // pin: frags issued before pc

        // ---- stream pc tile into LDS (async, hidden under MFMA) ----
        int rsub = lane >> 5, csub = lane & 31;   // 2 rows x 32 float4 per instr
        #pragma unroll
        for (int c = 0; c < 16; ++c) {
            int row = wave * 32 + c * 2;
            const float* src = pc + (size_t)(i0 + row + rsub) * KN + j0 + csub * 4;
            gload_lds16(src, sm.u.pcT + row * 128);
        }

        // ---- MFMA (waits only on fragments, not pc) ----
        f32x4 acc4[4][4];
        #pragma unroll
        for (int mi = 0; mi < 4; ++mi)
            #pragma unroll
            for (int nj = 0; nj < 4; ++nj)
                acc4[mi][nj] = (f32x4){0.f, 0.f, 0.f, 0.f};
        #pragma unroll
        for (int kk = 0; kk < 4; ++kk)
            #pragma unroll
            for (int mi = 0; mi < 4; ++mi)
                #pragma unroll
                for (int nj = 0; nj < 4; ++nj)
                    acc4[mi][nj] = __builtin_amdgcn_mfma_f32_16x16x32_bf16(
                        afr[kk][mi], bfr[kk][nj], acc4[mi][nj], 0, 0, 0);

        __syncthreads();   // drains vmcnt(0): pc tile + sqi/sqj visible

        // ---- epilogue: pc from LDS, apply to acc4 ----
        float sj0 = sm.u.sqj[wc + lr],      sj1 = sm.u.sqj[wc + 16 + lr];
        float sj2 = sm.u.sqj[wc + 32 + lr], sj3 = sm.u.sqj[wc + 48 + lr];
        float part = 0.f;
        #pragma unroll
        for (int mi = 0; mi < 4; ++mi) {
            #pragma unroll
            for (int v = 0; v < 4; ++v) {       // C/D row = (lane>>4)*4 + v
                int row = wr + 16 * mi + lg * 4 + v;
                float si = sm.u.sqi[row];
                const float* prow = sm.u.pcT + row * 128 + wc + lr;
                float p0 = prow[0], p1 = prow[16], p2 = prow[32], p3 = prow[48];
                float sq0 = fmaxf(si + sj0 - 2.f * acc4[mi][0][v], 0.f);
                float sq1 = fmaxf(si + sj1 - 2.f * acc4[mi][1][v], 0.f);
                float sq2 = fmaxf(si + sj2 - 2.f * acc4[mi][2][v], 0.f);
                float sq3 = fmaxf(si + sj3 - 2.f * acc4[mi][3][v], 0.f);
                float d0 = sqrtf(sq0), d1 = sqrtf(sq1);
                float d2 = sqrtf(sq2), d3 = sqrtf(sq3);
                float t0 = fmaf(p0, d0, __expf(-d0));
                float t1 = fmaf(p1, d1, __expf(-d1));
                float t2 = fmaf(p2, d2, __expf(-d2));
                float t3 = fmaf(p3, d3, __expf(-d3));
                part += (p0 != 0.f) ? t0 : 0.f;
                part += (p1 != 0.f) ? t1 : 0.f;
                part += (p2 != 0.f) ? t2 : 0.f;
                part += (p3 != 0.f) ? t3 : 0.f;
            }
        }
        #pragma unroll
        for (int off = 32; off > 0; off >>= 1) part += __shfl_down(part, off, 64);
        if (lane == 0) sm.u.wred[wave] = part;
        __syncthreads();
        if (t == 0)
            puns[blk] = (sm.u.wred[0] + sm.u.wred[1]) + (sm.u.wred[2] + sm.u.wred[3]);
        return;
    }

    // ================= supervised via P-gather =================
    int b = blk - 1024;
    for (int i = t; i < LN; i += 256) sm.s.sidx[i] = reads[b * LN + i];
    __syncthreads();
    const float4* P4 = (const float4*)P;
    size_t o0 = (size_t)sm.s.sidx[t] * 3;
    size_t o1 = (size_t)sm.s.sidx[t + 256] * 3;
    float4 a0 = P4[o0], b0 = P4[o0 + 1], c0 = P4[o0 + 2];
    float4 a1 = P4[o1], b1 = P4[o1 + 1], c1 = P4[o1 + 2];
    float s[12] = { a0.x + a1.x, a0.y + a1.y, a0.z + a1.z, a0.w + a1.w,
                    b0.x + b1.x, b0.y + b1.y, b0.z + b1.z, b0.w + b1.w,
                    c0.x + c1.x, c0.y + c1.y, c0.z + c1.z, c0.w + c1.w };
    #pragma unroll
    for (int off = 32; off > 0; off >>= 1)
        #pragma unroll
        for (int i = 0; i < 12; ++i) s[i] += __shfl_down(s[i], off, 64);
    int lane = t & 63, wave = t >> 6;
    if (lane == 0)
        #pragma unroll
        for (int i = 0; i < 12; ++i) sm.s.wredS[wave][i] = s[i];
    __syncthreads();
    if (t < CN)
        sm.s.slog[t] = sm.s.wredS[0][t] + sm.s.wredS[1][t]
                     + sm.s.wredS[2][t] + sm.s.wredS[3][t];
    __syncthreads();
    if (t == 0) {
        float m = sm.s.slog[0];
        #pragma unroll
        for (int c = 1; c < CN; ++c) m = fmaxf(m, sm.s.slog[c]);
        float se = 0.f;
        #pragma unroll
        for (int c = 0; c < CN; ++c) se += __expf(sm.s.slog[c] - m);
        float lse = m + __logf(se);
        psup[b] = -(sm.s.slog[labels[b]] - lse);
    }
}

// ---------------- K3: final reduce + combine -----------------------------------
__global__ __launch_bounds__(256) void w2v_final(const float* __restrict__ psup,
                                                 const float* __restrict__ puns,
                                                 const float* __restrict__ delta,
                                                 float* __restrict__ out) {
    __shared__ float r1[4], r2[4];
    int t = threadIdx.x;
    float a = 0.f, bsum = 0.f;
    for (int i = t; i < BN; i += 256)   a += psup[i];
    for (int i = t; i < 1024; i += 256) bsum += puns[i];
    #pragma unroll
    for (int off = 32; off > 0; off >>= 1) {
        a += __shfl_down(a, off, 64);
        bsum += __shfl_down(bsum, off, 64);
    }
    int lane = t & 63, wave = t >> 6;
    if (lane == 0) { r1[wave] = a; r2[wave] = bsum; }
    __syncthreads();
    if (t == 0) {
        float sup = (r1[0] + r1[1]) + (r1[2] + r1[3]);
        float uns = ((r2[0] + r2[1]) + (r2[2] + r2[3])) * (1.f / 16777216.f);
        float d = delta[0];
        out[0] = d * sup + (1.f - d) * uns;
    }
}

extern "C" void kernel_launch(void* const* d_in, const int* in_sizes, int n_in,
                              void* d_out, int out_size, void* d_ws, size_t ws_size,
                              hipStream_t stream) {
    const float* pc     = (const float*)d_in[0];
    const int*   reads  = (const int*)  d_in[1];
    const int*   labels = (const int*)  d_in[2];
    const float* delta  = (const float*)d_in[3];
    const float* embs   = (const float*)d_in[4];
    const float* W      = (const float*)d_in[5];
    float* out = (float*)d_out;

    char* ws = (char*)d_ws;
    float* sqn  = (float*)ws;                         // 4096 f32       @ 0
    float* P    = (float*)(ws + 16384);               // 4096x12 f32    @ 16384
    short* ebf  = (short*)(ws + 212992);              // 4096x128 bf16  @ 212992
    float* psup = (float*)(ws + 1261568);             // 1000 f32
    float* puns = (float*)(ws + 1265664);             // 1024 f32

    w2v_prep<<<576, 256, 0, stream>>>(embs, W, sqn, ebf, P);
    w2v_main<<<2024, 256, 0, stream>>>(ebf, sqn, pc, P, reads, labels, psup, puns);
    w2v_final<<<1, 256, 0, stream>>>(psup, puns, delta, out);
}